// Round 3
// baseline (698.798 us; speedup 1.0000x reference)
//
#include <hip/hip_runtime.h>
#include <cmath>
#include <cstdint>

// Set2Set, fixed geometry: N=100000 nodes, F=512, G=1000 graphs, 4 iterations.
#define FF   512
#define G4F  2048          // 4F
#define G2F  1024          // 2F
#define KTOT 1536          // 3F  (GEMM K = [q_star | h])
#define MPAD 1024          // G padded to a 64-row multiple for the GEMM
#define NITER 4

typedef __attribute__((ext_vector_type(8))) short bf16x8;  // 8 bf16 in 4 VGPRs
typedef __attribute__((ext_vector_type(4))) float f32x4;

// fp32 -> bf16 (RNE) and back, pure bit ops (no NaN in this workload).
__device__ __forceinline__ ushort f2bf(float x) {
  uint32_t u = __float_as_uint(x);
  return (ushort)((u + 0x7FFFu + ((u >> 16) & 1u)) >> 16);
}
__device__ __forceinline__ float bf2f(ushort b) {
  return __uint_as_float(((uint32_t)b) << 16);
}

// ---------------------------------------------------------------------------
// Segment boundaries from the (sorted, constant) node->graph index.
// ---------------------------------------------------------------------------
__global__ void seg_bounds_kernel(const int* __restrict__ idx, int N,
                                  int* __restrict__ segs, int* __restrict__ sege) {
  int n = blockIdx.x * blockDim.x + threadIdx.x;
  if (n >= N) return;
  int g = idx[n];
  if (n == 0     || idx[n-1] != g) segs[g] = n;
  if (n == N-1   || idx[n+1] != g) sege[g] = n + 1;
}

// ---------------------------------------------------------------------------
// One-time weight prep: W = [Wk;Wr] [1536][2048] fp32  ->  transposed split
// Wt_hi/Wt_lo [2048][1536] bf16 (k-contiguous = MFMA B-operand layout).
// 32x32 LDS transpose, coalesced on both sides.
// ---------------------------------------------------------------------------
__global__ __launch_bounds__(256) void prep_w_kernel(
    const float* __restrict__ Wk, const float* __restrict__ Wr,
    ushort* __restrict__ Wt_hi, ushort* __restrict__ Wt_lo) {
  __shared__ float t[32][33];
  int k0 = blockIdx.x * 32;          // 0..1535
  int n0 = blockIdx.y * 32;          // 0..2047
  int tx = threadIdx.x & 31, ty = threadIdx.x >> 5;   // ty 0..7
  #pragma unroll
  for (int i = 0; i < 4; ++i) {
    int k = k0 + ty + 8 * i;
    const float* srow = (k < 1024) ? (Wk + (size_t)k * 2048)
                                   : (Wr + (size_t)(k - 1024) * 2048);
    t[ty + 8 * i][tx] = srow[n0 + tx];
  }
  __syncthreads();
  #pragma unroll
  for (int i = 0; i < 4; ++i) {
    int r = ty + 8 * i;              // n offset within tile
    float v = t[tx][r];              // bank-conflict-free (33 stride)
    ushort hi = f2bf(v);
    ushort lo = f2bf(v - bf2f(hi));
    size_t o = (size_t)(n0 + r) * KTOT + k0 + tx;
    Wt_hi[o] = hi;
    Wt_lo[o] = lo;
  }
}

// ---------------------------------------------------------------------------
// Per-iteration A prep: A = [q_star | h] fp32 -> A_hi/A_lo [MPAD][1536] bf16.
// Rows >= G are left as-is (tiny garbage values; their z rows are never read).
// ---------------------------------------------------------------------------
__global__ __launch_bounds__(256) void prep_a_kernel(
    const float* __restrict__ qstar, const float* __restrict__ h,
    ushort* __restrict__ A_hi, ushort* __restrict__ A_lo, int G) {
  int i = blockIdx.x * blockDim.x + threadIdx.x;       // one thread per 4 elems
  int perRow = KTOT / 4;                               // 384
  if (i >= G * perRow) return;
  int row = i / perRow;
  int c4  = (i - row * perRow) * 4;                    // never straddles 1024
  const float* src = (c4 < G2F) ? (qstar + (size_t)row * G2F + c4)
                                : (h     + (size_t)row * FF  + (c4 - G2F));
  float4 v = *(const float4*)src;
  ushort4 hh, ll;
  hh.x = f2bf(v.x); ll.x = f2bf(v.x - bf2f(hh.x));
  hh.y = f2bf(v.y); ll.y = f2bf(v.y - bf2f(hh.y));
  hh.z = f2bf(v.z); ll.z = f2bf(v.z - bf2f(hh.z));
  hh.w = f2bf(v.w); ll.w = f2bf(v.w - bf2f(hh.w));
  size_t o = (size_t)row * KTOT + c4;
  *(ushort4*)(A_hi + o) = hh;
  *(ushort4*)(A_lo + o) = ll;
}

// ---------------------------------------------------------------------------
// z[MPAD,2048] = A * B via split-bf16 MFMA (hi*hi + hi*lo + lo*hi).
// 64x64 tile, BK=32, 4 waves (2x2), wave tile 32x32 -> 2x2 subtiles of
// mfma_f32_16x16x32_bf16. LDS rows padded to 40 ushorts (2-way ~free).
// A-frag: lane l holds A[row=l&15][k=(l>>4)*8 ..+8); B-frag from Wt[n][k]:
// lane l holds B[k=(l>>4)*8..][col=l&15]; C/D: col=lane&15, row=(lane>>4)*4+r
// (m89/m91-verified layouts).
// ---------------------------------------------------------------------------
#define GBM 64
#define GBN 64
#define GBK 32
#define LDP 40   // padded row length (ushorts)

__global__ __launch_bounds__(256) void gemm_mfma_kernel(
    const ushort* __restrict__ A_hi, const ushort* __restrict__ A_lo,
    const ushort* __restrict__ Wt_hi, const ushort* __restrict__ Wt_lo,
    float* __restrict__ z) {
  __shared__ ushort Ah[GBM][LDP], Al[GBM][LDP], Bh[GBN][LDP], Bl[GBN][LDP];

  int row0 = blockIdx.x * GBM;
  int col0 = blockIdx.y * GBN;
  int tid  = threadIdx.x, lane = tid & 63, wid = tid >> 6;
  int wr = wid >> 1, wc = wid & 1;       // 2x2 wave grid
  int sr = tid >> 2, sk = (tid & 3) * 8; // staging: row 0..63, k-offset

  const ushort* pa_h = A_hi  + (size_t)(row0 + sr) * KTOT + sk;
  const ushort* pa_l = A_lo  + (size_t)(row0 + sr) * KTOT + sk;
  const ushort* pb_h = Wt_hi + (size_t)(col0 + sr) * KTOT + sk;
  const ushort* pb_l = Wt_lo + (size_t)(col0 + sr) * KTOT + sk;

  f32x4 acc[2][2] = {};

  for (int k0 = 0; k0 < KTOT; k0 += GBK) {
    bf16x8 va_h = *(const bf16x8*)(pa_h + k0);
    bf16x8 va_l = *(const bf16x8*)(pa_l + k0);
    bf16x8 vb_h = *(const bf16x8*)(pb_h + k0);
    bf16x8 vb_l = *(const bf16x8*)(pb_l + k0);
    *(bf16x8*)&Ah[sr][sk] = va_h;
    *(bf16x8*)&Al[sr][sk] = va_l;
    *(bf16x8*)&Bh[sr][sk] = vb_h;
    *(bf16x8*)&Bl[sr][sk] = vb_l;
    __syncthreads();

    int ar = wr * 32 + (lane & 15);
    int bc = wc * 32 + (lane & 15);
    int ko = (lane >> 4) * 8;
    bf16x8 ah[2], al[2], bh[2], bl[2];
    ah[0] = *(const bf16x8*)&Ah[ar][ko];      al[0] = *(const bf16x8*)&Al[ar][ko];
    ah[1] = *(const bf16x8*)&Ah[ar + 16][ko]; al[1] = *(const bf16x8*)&Al[ar + 16][ko];
    bh[0] = *(const bf16x8*)&Bh[bc][ko];      bl[0] = *(const bf16x8*)&Bl[bc][ko];
    bh[1] = *(const bf16x8*)&Bh[bc + 16][ko]; bl[1] = *(const bf16x8*)&Bl[bc + 16][ko];

    #pragma unroll
    for (int mr = 0; mr < 2; ++mr)
      #pragma unroll
      for (int nc = 0; nc < 2; ++nc) {
        acc[mr][nc] = __builtin_amdgcn_mfma_f32_16x16x32_bf16(ah[mr], bh[nc], acc[mr][nc], 0, 0, 0);
        acc[mr][nc] = __builtin_amdgcn_mfma_f32_16x16x32_bf16(ah[mr], bl[nc], acc[mr][nc], 0, 0, 0);
        acc[mr][nc] = __builtin_amdgcn_mfma_f32_16x16x32_bf16(al[mr], bh[nc], acc[mr][nc], 0, 0, 0);
      }
    __syncthreads();
  }

  int cr = (lane >> 4) * 4, cc = lane & 15;
  #pragma unroll
  for (int mr = 0; mr < 2; ++mr)
    #pragma unroll
    for (int nc = 0; nc < 2; ++nc) {
      float* zp = z + (size_t)(row0 + wr * 32 + mr * 16 + cr) * G4F
                    + col0 + wc * 32 + nc * 16 + cc;
      #pragma unroll
      for (int r = 0; r < 4; ++r) zp[(size_t)r * G4F] = acc[mr][nc][r];
    }
}

// ---------------------------------------------------------------------------
// LSTM gates (Keras order i,f,g,o). zero_z=1: first iteration, z = bias and
// c_old = 0 (z/c are never read).
// ---------------------------------------------------------------------------
__global__ __launch_bounds__(256) void gates_kernel(
    const float* __restrict__ z, const float* __restrict__ bias,
    float* __restrict__ h, float* __restrict__ c, int G, int zero_z) {
  int i = blockIdx.x * blockDim.x + threadIdx.x;
  if (i >= G * FF) return;
  int g = i >> 9;
  int j = i & (FF - 1);
  float zi = bias[j], zf = bias[FF + j], zg = bias[2*FF + j], zo = bias[3*FF + j];
  float cold = 0.f;
  if (!zero_z) {
    const float* zr = z + (size_t)g * G4F;
    zi += zr[j]; zf += zr[FF + j]; zg += zr[2*FF + j]; zo += zr[3*FF + j];
    cold = c[i];
  }
  float ig = 1.f / (1.f + expf(-zi));
  float fg = 1.f / (1.f + expf(-zf));
  float gg = tanhf(zg);
  float og = 1.f / (1.f + expf(-zo));
  float cn = fg * cold + ig * gg;
  float hn = og * tanhf(cn);
  c[i] = cn;
  h[i] = hn;
}

// ---------------------------------------------------------------------------
// Per-graph attention + readout (one 256-thread block per graph, online
// softmax over 512-node chunks; second x read is chunk-resident in L2).
// ---------------------------------------------------------------------------
#define CHUNK 512

__global__ __launch_bounds__(256) void attn_readout_kernel(
    const float* __restrict__ x, const float* __restrict__ h,
    const int* __restrict__ segs, const int* __restrict__ sege,
    float* __restrict__ qs_out) {
  int g = blockIdx.x;
  int s = segs[g], e = sege[g];
  int tid = threadIdx.x;
  int wid = tid >> 6, lane = tid & 63;

  __shared__ float ew[CHUNK];
  __shared__ float red[4];
  __shared__ float sh_m, sh_d, sh_scale, sh_mnew;

  float q[8];
  {
    const float4* qp = (const float4*)(h + (size_t)g * FF);
    float4 t0 = qp[lane * 2], t1 = qp[lane * 2 + 1];
    q[0]=t0.x; q[1]=t0.y; q[2]=t0.z; q[3]=t0.w;
    q[4]=t1.x; q[5]=t1.y; q[6]=t1.z; q[7]=t1.w;
  }
  if (tid == 0) { sh_m = -INFINITY; sh_d = 0.f; }
  float2 racc = make_float2(0.f, 0.f);
  __syncthreads();

  for (int cs = s; cs < e; cs += CHUNK) {
    int ce = cs + CHUNK; if (ce > e) ce = e;
    int cnt = ce - cs;

    for (int i = cs + wid; i < ce; i += 4) {
      const float4* xp = (const float4*)(x + (size_t)i * FF);
      float4 x0 = xp[lane * 2], x1 = xp[lane * 2 + 1];
      float p = x0.x*q[0] + x0.y*q[1] + x0.z*q[2] + x0.w*q[3]
              + x1.x*q[4] + x1.y*q[5] + x1.z*q[6] + x1.w*q[7];
      #pragma unroll
      for (int off = 32; off; off >>= 1) p += __shfl_xor(p, off);
      if (lane == 0) ew[i - cs] = p;
    }
    __syncthreads();

    float lm = -INFINITY;
    for (int i = tid; i < cnt; i += 256) lm = fmaxf(lm, ew[i]);
    #pragma unroll
    for (int off = 32; off; off >>= 1) lm = fmaxf(lm, __shfl_xor(lm, off));
    if (lane == 0) red[wid] = lm;
    __syncthreads();
    if (tid == 0) {
      float mc   = fmaxf(fmaxf(red[0], red[1]), fmaxf(red[2], red[3]));
      float mold = sh_m;
      float mnew = fmaxf(mold, mc);
      sh_mnew  = mnew;
      sh_scale = (mold == -INFINITY) ? 0.f : expf(mold - mnew);
      sh_m     = mnew;
    }
    __syncthreads();

    float mnew = sh_mnew;
    float ls = 0.f;
    for (int i = tid; i < cnt; i += 256) {
      float w = expf(ew[i] - mnew);
      ew[i] = w;
      ls += w;
    }
    #pragma unroll
    for (int off = 32; off; off >>= 1) ls += __shfl_xor(ls, off);
    if (lane == 0) red[wid] = ls;
    __syncthreads();

    float scale = sh_scale;
    if (tid == 0) sh_d = sh_d * scale + (red[0] + red[1] + red[2] + red[3]);

    racc.x *= scale; racc.y *= scale;
    for (int i = cs; i < ce; ++i) {
      float  w  = ew[i - cs];
      float2 xv = *(const float2*)(x + (size_t)i * FF + 2 * tid);
      racc.x += w * xv.x;
      racc.y += w * xv.y;
    }
    __syncthreads();
  }

  float d = sh_d;
  {
    float2 hv = *(const float2*)(h + (size_t)g * FF + 2 * tid);
    *(float2*)(qs_out + (size_t)g * G2F + 2 * tid) = hv;
  }
  float inv = (d > 0.f) ? 1.f / d : 0.f;
  float2 rv = make_float2(racc.x * inv, racc.y * inv);
  *(float2*)(qs_out + (size_t)g * G2F + FF + 2 * tid) = rv;
}

// ---------------------------------------------------------------------------
extern "C" void kernel_launch(void* const* d_in, const int* in_sizes, int n_in,
                              void* d_out, int out_size, void* d_ws, size_t ws_size,
                              hipStream_t stream) {
  const float* x    = (const float*)d_in[0];
  const int*   idx  = (const int*)d_in[1];
  const float* Wk   = (const float*)d_in[2];
  const float* Wr   = (const float*)d_in[3];
  const float* bias = (const float*)d_in[4];
  int N = in_sizes[1];
  int F = in_sizes[4] / 4;          // 512 (kernels hard-assume this)
  int G = out_size / (2 * F);       // 1000
  (void)n_in; (void)ws_size; (void)F;

  float* qstar = (float*)d_out;     // q_star lives in d_out (fully rewritten each iter)

  // workspace carve (all chunks 16B-multiple):
  char* p = (char*)d_ws;
  float*  h     = (float*)p;            p += (size_t)G * FF * 4;        // 2.048 MB
  float*  c     = (float*)p;            p += (size_t)G * FF * 4;        // 2.048 MB
  float*  z     = (float*)p;            p += (size_t)MPAD * G4F * 4;    // 8.389 MB
  ushort* A_hi  = (ushort*)p;           p += (size_t)MPAD * KTOT * 2;   // 3.146 MB
  ushort* A_lo  = (ushort*)p;           p += (size_t)MPAD * KTOT * 2;
  ushort* Wt_hi = (ushort*)p;           p += (size_t)G4F * KTOT * 2;    // 6.291 MB
  ushort* Wt_lo = (ushort*)p;           p += (size_t)G4F * KTOT * 2;
  int*    segs  = (int*)p;              p += (size_t)G * 4;
  int*    sege  = (int*)p;

  hipMemsetAsync(segs, 0, 2 * sizeof(int) * (size_t)G, stream);
  seg_bounds_kernel<<<(N + 255) / 256, 256, 0, stream>>>(idx, N, segs, sege);

  // one-time weight transpose+split (constant across iterations)
  prep_w_kernel<<<dim3(KTOT / 32, G4F / 32), 256, 0, stream>>>(Wk, Wr, Wt_hi, Wt_lo);

  dim3 ggrid((G + GBM - 1) / GBM, G4F / GBN);   // 16 x 32 = 512 blocks

  for (int it = 0; it < NITER; ++it) {
    if (it == 0) {
      // q_star = h = c = 0  =>  z = bias; GEMM provably skippable.
      gates_kernel<<<(G * FF + 255) / 256, 256, 0, stream>>>(z, bias, h, c, G, 1);
    } else {
      prep_a_kernel<<<(G * (KTOT / 4) + 255) / 256, 256, 0, stream>>>(qstar, h, A_hi, A_lo, G);
      gemm_mfma_kernel<<<ggrid, 256, 0, stream>>>(A_hi, A_lo, Wt_hi, Wt_lo, z);
      gates_kernel<<<(G * FF + 255) / 256, 256, 0, stream>>>(z, bias, h, c, G, 0);
    }
    attn_readout_kernel<<<G, 256, 0, stream>>>(x, h, segs, sege, qstar);
  }
}

// Round 4
// 548.342 us; speedup vs baseline: 1.2744x; 1.2744x over previous
//
#include <hip/hip_runtime.h>
#include <cmath>
#include <cstdint>

// Set2Set, fixed geometry: N=100000 nodes, F=512, G=1000 graphs, 4 iterations.
#define FF   512
#define G4F  2048          // 4F
#define G2F  1024          // 2F
#define KTOT 1536          // 3F  (GEMM K = [q_star | h])
#define MPAD 1024          // G padded to a 64-row multiple for the GEMM
#define NITER 4

typedef __attribute__((ext_vector_type(8))) short bf16x8;  // 8 bf16 in 4 VGPRs
typedef __attribute__((ext_vector_type(4))) float f32x4;

// fp32 -> bf16 (RNE) and back, pure bit ops (no NaN in this workload).
__device__ __forceinline__ ushort f2bf(float x) {
  uint32_t u = __float_as_uint(x);
  return (ushort)((u + 0x7FFFu + ((u >> 16) & 1u)) >> 16);
}
__device__ __forceinline__ float bf2f(ushort b) {
  return __uint_as_float(((uint32_t)b) << 16);
}

// ---------------------------------------------------------------------------
// Segment boundaries from the (sorted, constant) node->graph index.
// ---------------------------------------------------------------------------
__global__ void seg_bounds_kernel(const int* __restrict__ idx, int N,
                                  int* __restrict__ segs, int* __restrict__ sege) {
  int n = blockIdx.x * blockDim.x + threadIdx.x;
  if (n >= N) return;
  int g = idx[n];
  if (n == 0     || idx[n-1] != g) segs[g] = n;
  if (n == N-1   || idx[n+1] != g) sege[g] = n + 1;
}

// ---------------------------------------------------------------------------
// One-time weight prep: W = [Wk;Wr] [1536][2048] fp32  ->  transposed split
// Wt_hi/Wt_lo [2048][1536] bf16 (k-contiguous = MFMA B-operand layout).
// ---------------------------------------------------------------------------
__global__ __launch_bounds__(256) void prep_w_kernel(
    const float* __restrict__ Wk, const float* __restrict__ Wr,
    ushort* __restrict__ Wt_hi, ushort* __restrict__ Wt_lo) {
  __shared__ float t[32][33];
  int k0 = blockIdx.x * 32;          // 0..1535
  int n0 = blockIdx.y * 32;          // 0..2047
  int tx = threadIdx.x & 31, ty = threadIdx.x >> 5;   // ty 0..7
  #pragma unroll
  for (int i = 0; i < 4; ++i) {
    int k = k0 + ty + 8 * i;
    const float* srow = (k < 1024) ? (Wk + (size_t)k * 2048)
                                   : (Wr + (size_t)(k - 1024) * 2048);
    t[ty + 8 * i][tx] = srow[n0 + tx];
  }
  __syncthreads();
  #pragma unroll
  for (int i = 0; i < 4; ++i) {
    int r = ty + 8 * i;              // n offset within tile
    float v = t[tx][r];              // bank-conflict-free (33 stride)
    ushort hi = f2bf(v);
    ushort lo = f2bf(v - bf2f(hi));
    size_t o = (size_t)(n0 + r) * KTOT + k0 + tx;
    Wt_hi[o] = hi;
    Wt_lo[o] = lo;
  }
}

// ---------------------------------------------------------------------------
// Per-iteration A prep: A = [q_star | h] fp32 -> A_hi/A_lo [MPAD][1536] bf16.
// ---------------------------------------------------------------------------
__global__ __launch_bounds__(256) void prep_a_kernel(
    const float* __restrict__ qstar, const float* __restrict__ h,
    ushort* __restrict__ A_hi, ushort* __restrict__ A_lo, int G) {
  int i = blockIdx.x * blockDim.x + threadIdx.x;       // one thread per 4 elems
  int perRow = KTOT / 4;                               // 384
  if (i >= G * perRow) return;
  int row = i / perRow;
  int c4  = (i - row * perRow) * 4;                    // never straddles 1024
  const float* src = (c4 < G2F) ? (qstar + (size_t)row * G2F + c4)
                                : (h     + (size_t)row * FF  + (c4 - G2F));
  float4 v = *(const float4*)src;
  ushort4 hh, ll;
  hh.x = f2bf(v.x); ll.x = f2bf(v.x - bf2f(hh.x));
  hh.y = f2bf(v.y); ll.y = f2bf(v.y - bf2f(hh.y));
  hh.z = f2bf(v.z); ll.z = f2bf(v.z - bf2f(hh.z));
  hh.w = f2bf(v.w); ll.w = f2bf(v.w - bf2f(hh.w));
  size_t o = (size_t)row * KTOT + c4;
  *(ushort4*)(A_hi + o) = hh;
  *(ushort4*)(A_lo + o) = ll;
}

// ---------------------------------------------------------------------------
// z[MPAD,2048] = A * B via split-bf16 MFMA (hi*hi + hi*lo + lo*hi).
// 64x64 tile, BK=32, 4 waves (2x2), wave tile 32x32.
// ---------------------------------------------------------------------------
#define GBM 64
#define GBN 64
#define GBK 32
#define LDP 40   // padded row length (ushorts)

__global__ __launch_bounds__(256) void gemm_mfma_kernel(
    const ushort* __restrict__ A_hi, const ushort* __restrict__ A_lo,
    const ushort* __restrict__ Wt_hi, const ushort* __restrict__ Wt_lo,
    float* __restrict__ z) {
  __shared__ ushort Ah[GBM][LDP], Al[GBM][LDP], Bh[GBN][LDP], Bl[GBN][LDP];

  int row0 = blockIdx.x * GBM;
  int col0 = blockIdx.y * GBN;
  int tid  = threadIdx.x, lane = tid & 63, wid = tid >> 6;
  int wr = wid >> 1, wc = wid & 1;       // 2x2 wave grid
  int sr = tid >> 2, sk = (tid & 3) * 8; // staging: row 0..63, k-offset

  const ushort* pa_h = A_hi  + (size_t)(row0 + sr) * KTOT + sk;
  const ushort* pa_l = A_lo  + (size_t)(row0 + sr) * KTOT + sk;
  const ushort* pb_h = Wt_hi + (size_t)(col0 + sr) * KTOT + sk;
  const ushort* pb_l = Wt_lo + (size_t)(col0 + sr) * KTOT + sk;

  f32x4 acc[2][2] = {};

  for (int k0 = 0; k0 < KTOT; k0 += GBK) {
    bf16x8 va_h = *(const bf16x8*)(pa_h + k0);
    bf16x8 va_l = *(const bf16x8*)(pa_l + k0);
    bf16x8 vb_h = *(const bf16x8*)(pb_h + k0);
    bf16x8 vb_l = *(const bf16x8*)(pb_l + k0);
    *(bf16x8*)&Ah[sr][sk] = va_h;
    *(bf16x8*)&Al[sr][sk] = va_l;
    *(bf16x8*)&Bh[sr][sk] = vb_h;
    *(bf16x8*)&Bl[sr][sk] = vb_l;
    __syncthreads();

    int ar = wr * 32 + (lane & 15);
    int bc = wc * 32 + (lane & 15);
    int ko = (lane >> 4) * 8;
    bf16x8 ah[2], al[2], bh[2], bl[2];
    ah[0] = *(const bf16x8*)&Ah[ar][ko];      al[0] = *(const bf16x8*)&Al[ar][ko];
    ah[1] = *(const bf16x8*)&Ah[ar + 16][ko]; al[1] = *(const bf16x8*)&Al[ar + 16][ko];
    bh[0] = *(const bf16x8*)&Bh[bc][ko];      bl[0] = *(const bf16x8*)&Bl[bc][ko];
    bh[1] = *(const bf16x8*)&Bh[bc + 16][ko]; bl[1] = *(const bf16x8*)&Bl[bc + 16][ko];

    #pragma unroll
    for (int mr = 0; mr < 2; ++mr)
      #pragma unroll
      for (int nc = 0; nc < 2; ++nc) {
        acc[mr][nc] = __builtin_amdgcn_mfma_f32_16x16x32_bf16(ah[mr], bh[nc], acc[mr][nc], 0, 0, 0);
        acc[mr][nc] = __builtin_amdgcn_mfma_f32_16x16x32_bf16(ah[mr], bl[nc], acc[mr][nc], 0, 0, 0);
        acc[mr][nc] = __builtin_amdgcn_mfma_f32_16x16x32_bf16(al[mr], bh[nc], acc[mr][nc], 0, 0, 0);
      }
    __syncthreads();
  }

  int cr = (lane >> 4) * 4, cc = lane & 15;
  #pragma unroll
  for (int mr = 0; mr < 2; ++mr)
    #pragma unroll
    for (int nc = 0; nc < 2; ++nc) {
      float* zp = z + (size_t)(row0 + wr * 32 + mr * 16 + cr) * G4F
                    + col0 + wc * 32 + nc * 16 + cc;
      #pragma unroll
      for (int r = 0; r < 4; ++r) zp[(size_t)r * G4F] = acc[mr][nc][r];
    }
}

// ---------------------------------------------------------------------------
// LSTM gates (Keras order i,f,g,o). Also writes the q-part of q_star
// (qs[g][0:512] = h_new) so the attention kernel only writes the r-part.
// ---------------------------------------------------------------------------
__global__ __launch_bounds__(256) void gates_kernel(
    const float* __restrict__ z, const float* __restrict__ bias,
    float* __restrict__ h, float* __restrict__ c, float* __restrict__ qs,
    int G, int zero_z) {
  int i = blockIdx.x * blockDim.x + threadIdx.x;
  if (i >= G * FF) return;
  int g = i >> 9;
  int j = i & (FF - 1);
  float zi = bias[j], zf = bias[FF + j], zg = bias[2*FF + j], zo = bias[3*FF + j];
  float cold = 0.f;
  if (!zero_z) {
    const float* zr = z + (size_t)g * G4F;
    zi += zr[j]; zf += zr[FF + j]; zg += zr[2*FF + j]; zo += zr[3*FF + j];
    cold = c[i];
  }
  float ig = 1.f / (1.f + expf(-zi));
  float fg = 1.f / (1.f + expf(-zf));
  float gg = tanhf(zg);
  float og = 1.f / (1.f + expf(-zo));
  float cn = fg * cold + ig * gg;
  float hn = og * tanhf(cn);
  c[i] = cn;
  h[i] = hn;
  qs[(size_t)g * G2F + j] = hn;
}

// ---------------------------------------------------------------------------
// Single-pass flash-style attention + readout. One block (4 waves) per graph;
// wave w handles nodes s+w, s+w+4, ... Each node's x-row lives in registers
// for BOTH the logit dot-product and the weighted accumulation -> x is read
// exactly once per iteration. Online softmax per wave (p is wave-uniform
// after the butterfly: fp add commutes bitwise, so all lanes agree and the
// rescale branch is uniform). Wave partials merged via LDS at the end.
// ---------------------------------------------------------------------------
__device__ __forceinline__ float dotq_reduce(const float4& a0, const float4& a1,
                                             const float4& q0, const float4& q1) {
  float p = a0.x*q0.x + a0.y*q0.y + a0.z*q0.z + a0.w*q0.w
          + a1.x*q1.x + a1.y*q1.y + a1.z*q1.z + a1.w*q1.w;
  #pragma unroll
  for (int off = 32; off; off >>= 1) p += __shfl_xor(p, off);
  return p;
}

__global__ __launch_bounds__(256) void attn_fused_kernel(
    const float* __restrict__ x, const float* __restrict__ h,
    const int* __restrict__ segs, const int* __restrict__ sege,
    float* __restrict__ qs_out) {
  int g = blockIdx.x;
  int s = segs[g], e = sege[g];
  int tid = threadIdx.x, wid = tid >> 6, lane = tid & 63;

  __shared__ float wm[4], wd[4];
  __shared__ float wr[4][FF];

  // q = h[g]; lane owns cols [4*lane,4*lane+4) and [256+4*lane, ...+4)
  float4 q0, q1;
  {
    const float* hp = h + (size_t)g * FF;
    q0 = *(const float4*)(hp + 4 * lane);
    q1 = *(const float4*)(hp + 256 + 4 * lane);
  }

  float m = -INFINITY, d = 0.f;
  float4 r0 = make_float4(0.f, 0.f, 0.f, 0.f);
  float4 r1 = make_float4(0.f, 0.f, 0.f, 0.f);

  auto upd = [&](float p, const float4& a0, const float4& a1) {
    if (p > m) {                       // wave-uniform branch
      float sc = __expf(m - p);        // m=-inf first time -> 0
      d *= sc;
      r0.x *= sc; r0.y *= sc; r0.z *= sc; r0.w *= sc;
      r1.x *= sc; r1.y *= sc; r1.z *= sc; r1.w *= sc;
      m = p;
    }
    float w = __expf(p - m);
    d += w;
    r0.x += w * a0.x; r0.y += w * a0.y; r0.z += w * a0.z; r0.w += w * a0.w;
    r1.x += w * a1.x; r1.y += w * a1.y; r1.z += w * a1.z; r1.w += w * a1.w;
  };

  int i = s + wid;
  for (; i + 4 < e; i += 8) {          // unroll 2: rows i and i+4 in flight
    const float* xa = x + (size_t)i * FF;
    const float* xb = x + (size_t)(i + 4) * FF;
    float4 a0 = *(const float4*)(xa + 4 * lane);
    float4 a1 = *(const float4*)(xa + 256 + 4 * lane);
    float4 b0 = *(const float4*)(xb + 4 * lane);
    float4 b1 = *(const float4*)(xb + 256 + 4 * lane);
    float pa = dotq_reduce(a0, a1, q0, q1);
    float pb = dotq_reduce(b0, b1, q0, q1);
    upd(pa, a0, a1);
    upd(pb, b0, b1);
  }
  if (i < e) {
    const float* xa = x + (size_t)i * FF;
    float4 a0 = *(const float4*)(xa + 4 * lane);
    float4 a1 = *(const float4*)(xa + 256 + 4 * lane);
    float pa = dotq_reduce(a0, a1, q0, q1);
    upd(pa, a0, a1);
  }

  // ---- merge 4 wave partials ----
  if (lane == 0) { wm[wid] = m; wd[wid] = d; }
  *(float4*)&wr[wid][4 * lane]       = r0;
  *(float4*)&wr[wid][256 + 4 * lane] = r1;
  __syncthreads();

  float m0 = wm[0], m1 = wm[1], m2 = wm[2], m3 = wm[3];
  float ms = fmaxf(fmaxf(m0, m1), fmaxf(m2, m3));
  float s0 = (m0 == -INFINITY) ? 0.f : __expf(m0 - ms);
  float s1 = (m1 == -INFINITY) ? 0.f : __expf(m1 - ms);
  float s2 = (m2 == -INFINITY) ? 0.f : __expf(m2 - ms);
  float s3 = (m3 == -INFINITY) ? 0.f : __expf(m3 - ms);
  float dt = wd[0]*s0 + wd[1]*s1 + wd[2]*s2 + wd[3]*s3;
  float inv = (dt > 0.f) ? 1.f / dt : 0.f;

  int cc = tid * 2;                    // 256 threads x 2 cols = 512
  float2 v0 = *(float2*)&wr[0][cc];
  float2 v1 = *(float2*)&wr[1][cc];
  float2 v2 = *(float2*)&wr[2][cc];
  float2 v3 = *(float2*)&wr[3][cc];
  float rx = (v0.x*s0 + v1.x*s1 + v2.x*s2 + v3.x*s3) * inv;
  float ry = (v0.y*s0 + v1.y*s1 + v2.y*s2 + v3.y*s3) * inv;
  *(float2*)(qs_out + (size_t)g * G2F + FF + cc) = make_float2(rx, ry);
}

// ---------------------------------------------------------------------------
extern "C" void kernel_launch(void* const* d_in, const int* in_sizes, int n_in,
                              void* d_out, int out_size, void* d_ws, size_t ws_size,
                              hipStream_t stream) {
  const float* x    = (const float*)d_in[0];
  const int*   idx  = (const int*)d_in[1];
  const float* Wk   = (const float*)d_in[2];
  const float* Wr   = (const float*)d_in[3];
  const float* bias = (const float*)d_in[4];
  int N = in_sizes[1];
  int F = in_sizes[4] / 4;          // 512 (kernels hard-assume this)
  int G = out_size / (2 * F);       // 1000
  (void)n_in; (void)ws_size; (void)F;

  float* qstar = (float*)d_out;     // q_star lives in d_out (fully rewritten each iter)

  // workspace carve (all chunks 16B-multiple):
  char* p = (char*)d_ws;
  float*  h     = (float*)p;            p += (size_t)G * FF * 4;
  float*  c     = (float*)p;            p += (size_t)G * FF * 4;
  float*  z     = (float*)p;            p += (size_t)MPAD * G4F * 4;
  ushort* A_hi  = (ushort*)p;           p += (size_t)MPAD * KTOT * 2;
  ushort* A_lo  = (ushort*)p;           p += (size_t)MPAD * KTOT * 2;
  ushort* Wt_hi = (ushort*)p;           p += (size_t)G4F * KTOT * 2;
  ushort* Wt_lo = (ushort*)p;           p += (size_t)G4F * KTOT * 2;
  int*    segs  = (int*)p;              p += (size_t)G * 4;
  int*    sege  = (int*)p;

  hipMemsetAsync(segs, 0, 2 * sizeof(int) * (size_t)G, stream);
  seg_bounds_kernel<<<(N + 255) / 256, 256, 0, stream>>>(idx, N, segs, sege);

  // one-time weight transpose+split (constant across iterations)
  prep_w_kernel<<<dim3(KTOT / 32, G4F / 32), 256, 0, stream>>>(Wk, Wr, Wt_hi, Wt_lo);

  dim3 ggrid((G + GBM - 1) / GBM, G4F / GBN);   // 16 x 32 = 512 blocks

  for (int it = 0; it < NITER; ++it) {
    if (it == 0) {
      // q_star = h = c = 0  =>  z = bias; GEMM provably skippable.
      gates_kernel<<<(G * FF + 255) / 256, 256, 0, stream>>>(z, bias, h, c, qstar, G, 1);
    } else {
      prep_a_kernel<<<(G * (KTOT / 4) + 255) / 256, 256, 0, stream>>>(qstar, h, A_hi, A_lo, G);
      gemm_mfma_kernel<<<ggrid, 256, 0, stream>>>(A_hi, A_lo, Wt_hi, Wt_lo, z);
      gates_kernel<<<(G * FF + 255) / 256, 256, 0, stream>>>(z, bias, h, c, qstar, G, 0);
    }
    attn_fused_kernel<<<G, 256, 0, stream>>>(x, h, segs, sege, qstar);
  }
}

// Round 8
// 502.950 us; speedup vs baseline: 1.3894x; 1.0903x over previous
//
#include <hip/hip_runtime.h>
#include <cmath>
#include <cstdint>

// Set2Set, fixed geometry: N=100000 nodes, F=512, G=1000 graphs, 4 iterations.
#define FF   512
#define G4F  2048          // 4F
#define G2F  1024          // 2F
#define KC   1024          // GEMM K after combining: z = h@(Wk_top+Wr) + r@Wk_bot
#define MPAD 1024          // G padded to a 64-row multiple for the GEMM
#define NITER 4

typedef __attribute__((ext_vector_type(8))) short bf16x8;  // 8 bf16 in 4 VGPRs
typedef __attribute__((ext_vector_type(4))) float f32x4;

// fp32 -> bf16 (RNE) and back, pure bit ops (no NaN in this workload).
__device__ __forceinline__ ushort f2bf(float x) {
  uint32_t u = __float_as_uint(x);
  return (ushort)((u + 0x7FFFu + ((u >> 16) & 1u)) >> 16);
}
__device__ __forceinline__ float bf2f(ushort b) {
  return __uint_as_float(((uint32_t)b) << 16);
}

// ---------------------------------------------------------------------------
// Segment boundaries from the (sorted, constant) node->graph index.
// ---------------------------------------------------------------------------
__global__ void seg_bounds_kernel(const int* __restrict__ idx, int N,
                                  int* __restrict__ segs, int* __restrict__ sege) {
  int n = blockIdx.x * blockDim.x + threadIdx.x;
  if (n >= N) return;
  int g = idx[n];
  if (n == 0     || idx[n-1] != g) segs[g] = n;
  if (n == N-1   || idx[n+1] != g) sege[g] = n + 1;
}

// ---------------------------------------------------------------------------
// One-time weight prep. Combined weight uses q_star=[h|r]:
//   z = h@(Wk[0:512]+Wr) + r@Wk[512:1024]
// Wt_c[n][k] (k-contiguous bf16 hi/lo, MFMA B layout):
//   k<512 : Wk[k][n] + Wr[k][n]     k>=512 : Wk[k][n]
// ---------------------------------------------------------------------------
__global__ __launch_bounds__(256) void prep_w_kernel(
    const float* __restrict__ Wk, const float* __restrict__ Wr,
    ushort* __restrict__ Wt_hi, ushort* __restrict__ Wt_lo) {
  __shared__ float t[32][33];
  int k0 = blockIdx.x * 32;          // 0..1023
  int n0 = blockIdx.y * 32;          // 0..2047
  int tx = threadIdx.x & 31, ty = threadIdx.x >> 5;   // ty 0..7
  #pragma unroll
  for (int i = 0; i < 4; ++i) {
    int k = k0 + ty + 8 * i;
    float v = Wk[(size_t)k * 2048 + n0 + tx];
    if (k < 512) v += Wr[(size_t)k * 2048 + n0 + tx];
    t[ty + 8 * i][tx] = v;
  }
  __syncthreads();
  #pragma unroll
  for (int i = 0; i < 4; ++i) {
    int r = ty + 8 * i;              // n offset within tile
    float v = t[tx][r];              // bank-conflict-free (33 stride)
    ushort hi = f2bf(v);
    ushort lo = f2bf(v - bf2f(hi));
    size_t o = (size_t)(n0 + r) * KC + k0 + tx;
    Wt_hi[o] = hi;
    Wt_lo[o] = lo;
  }
}

// ---------------------------------------------------------------------------
// z[MPAD,2048] = A * B via split-bf16 MFMA (hi*hi + hi*lo + lo*hi).
// A = [h | r] [MPAD][1024], written bf16-split by gates (h) and attn (r).
// 64x64 tile, BK=32, 4 waves (2x2), wave tile 32x32.
// ---------------------------------------------------------------------------
#define GBM 64
#define GBN 64
#define GBK 32
#define LDP 40   // padded row length (ushorts)

__global__ __launch_bounds__(256) void gemm_mfma_kernel(
    const ushort* __restrict__ A_hi, const ushort* __restrict__ A_lo,
    const ushort* __restrict__ Wt_hi, const ushort* __restrict__ Wt_lo,
    float* __restrict__ z) {
  __shared__ ushort Ah[GBM][LDP], Al[GBM][LDP], Bh[GBN][LDP], Bl[GBN][LDP];

  int row0 = blockIdx.x * GBM;
  int col0 = blockIdx.y * GBN;
  int tid  = threadIdx.x, lane = tid & 63, wid = tid >> 6;
  int wr = wid >> 1, wc = wid & 1;       // 2x2 wave grid
  int sr = tid >> 2, sk = (tid & 3) * 8; // staging: row 0..63, k-offset

  const ushort* pa_h = A_hi  + (size_t)(row0 + sr) * KC + sk;
  const ushort* pa_l = A_lo  + (size_t)(row0 + sr) * KC + sk;
  const ushort* pb_h = Wt_hi + (size_t)(col0 + sr) * KC + sk;
  const ushort* pb_l = Wt_lo + (size_t)(col0 + sr) * KC + sk;

  f32x4 acc[2][2] = {};

  for (int k0 = 0; k0 < KC; k0 += GBK) {
    bf16x8 va_h = *(const bf16x8*)(pa_h + k0);
    bf16x8 va_l = *(const bf16x8*)(pa_l + k0);
    bf16x8 vb_h = *(const bf16x8*)(pb_h + k0);
    bf16x8 vb_l = *(const bf16x8*)(pb_l + k0);
    *(bf16x8*)&Ah[sr][sk] = va_h;
    *(bf16x8*)&Al[sr][sk] = va_l;
    *(bf16x8*)&Bh[sr][sk] = vb_h;
    *(bf16x8*)&Bl[sr][sk] = vb_l;
    __syncthreads();

    int ar = wr * 32 + (lane & 15);
    int bc = wc * 32 + (lane & 15);
    int ko = (lane >> 4) * 8;
    bf16x8 ah[2], al[2], bh[2], bl[2];
    ah[0] = *(const bf16x8*)&Ah[ar][ko];      al[0] = *(const bf16x8*)&Al[ar][ko];
    ah[1] = *(const bf16x8*)&Ah[ar + 16][ko]; al[1] = *(const bf16x8*)&Al[ar + 16][ko];
    bh[0] = *(const bf16x8*)&Bh[bc][ko];      bl[0] = *(const bf16x8*)&Bl[bc][ko];
    bh[1] = *(const bf16x8*)&Bh[bc + 16][ko]; bl[1] = *(const bf16x8*)&Bl[bc + 16][ko];

    #pragma unroll
    for (int mr = 0; mr < 2; ++mr)
      #pragma unroll
      for (int nc = 0; nc < 2; ++nc) {
        acc[mr][nc] = __builtin_amdgcn_mfma_f32_16x16x32_bf16(ah[mr], bh[nc], acc[mr][nc], 0, 0, 0);
        acc[mr][nc] = __builtin_amdgcn_mfma_f32_16x16x32_bf16(ah[mr], bl[nc], acc[mr][nc], 0, 0, 0);
        acc[mr][nc] = __builtin_amdgcn_mfma_f32_16x16x32_bf16(al[mr], bh[nc], acc[mr][nc], 0, 0, 0);
      }
    __syncthreads();
  }

  int cr = (lane >> 4) * 4, cc = lane & 15;
  #pragma unroll
  for (int mr = 0; mr < 2; ++mr)
    #pragma unroll
    for (int nc = 0; nc < 2; ++nc) {
      float* zp = z + (size_t)(row0 + wr * 32 + mr * 16 + cr) * G4F
                    + col0 + wc * 32 + nc * 16 + cc;
      #pragma unroll
      for (int r = 0; r < 4; ++r) zp[(size_t)r * G4F] = acc[mr][nc][r];
    }
}

// ---------------------------------------------------------------------------
// LSTM gates (Keras order i,f,g,o). Writes h, c, the q-part of q_star, and
// the bf16-split h-part of the next GEMM's A matrix.
// ---------------------------------------------------------------------------
__global__ __launch_bounds__(256) void gates_kernel(
    const float* __restrict__ z, const float* __restrict__ bias,
    float* __restrict__ h, float* __restrict__ c, float* __restrict__ qs,
    ushort* __restrict__ A_hi, ushort* __restrict__ A_lo,
    int G, int zero_z) {
  int i = blockIdx.x * blockDim.x + threadIdx.x;
  if (i >= G * FF) return;
  int g = i >> 9;
  int j = i & (FF - 1);
  float zi = bias[j], zf = bias[FF + j], zg = bias[2*FF + j], zo = bias[3*FF + j];
  float cold = 0.f;
  if (!zero_z) {
    const float* zr = z + (size_t)g * G4F;
    zi += zr[j]; zf += zr[FF + j]; zg += zr[2*FF + j]; zo += zr[3*FF + j];
    cold = c[i];
  }
  float ig = 1.f / (1.f + expf(-zi));
  float fg = 1.f / (1.f + expf(-zf));
  float gg = tanhf(zg);
  float og = 1.f / (1.f + expf(-zo));
  float cn = fg * cold + ig * gg;
  float hn = og * tanhf(cn);
  c[i] = cn;
  h[i] = hn;
  qs[(size_t)g * G2F + j] = hn;
  ushort hh = f2bf(hn), ll = f2bf(hn - bf2f(hh));
  A_hi[(size_t)g * KC + j] = hh;
  A_lo[(size_t)g * KC + j] = ll;
}

// ---------------------------------------------------------------------------
// Single-pass flash-style attention + readout. One block (4 waves) per graph;
// wave w owns a CONTIGUOUS quarter of the segment (sequential streaming).
// Branchless unroll-4 online softmax: 4 rows in registers per iteration, one
// rescale per 4 rows, no control flow in the hot loop (loads pipeline).
// Writes qs_out r-part (fp32) and the bf16-split r-part of the GEMM A.
// ---------------------------------------------------------------------------
__device__ __forceinline__ float dotq_reduce(const float4& a0, const float4& a1,
                                             const float4& q0, const float4& q1) {
  float p = a0.x*q0.x + a0.y*q0.y + a0.z*q0.z + a0.w*q0.w
          + a1.x*q1.x + a1.y*q1.y + a1.z*q1.z + a1.w*q1.w;
  #pragma unroll
  for (int off = 32; off; off >>= 1) p += __shfl_xor(p, off);
  return p;   // wave-uniform (butterfly is lane-symmetric)
}

__global__ __launch_bounds__(256) void attn_fused_kernel(
    const float* __restrict__ x, const float* __restrict__ h,
    const int* __restrict__ segs, const int* __restrict__ sege,
    float* __restrict__ qs_out,
    ushort* __restrict__ A_hi, ushort* __restrict__ A_lo) {
  int g = blockIdx.x;
  int s = segs[g], e = sege[g];
  int tid = threadIdx.x, wid = tid >> 6, lane = tid & 63;

  __shared__ float wm[4], wd[4];
  __shared__ float wrs[4][FF];

  // q = h[g]; lane owns cols [4*lane,4*lane+4) and [256+4*lane, ...+4)
  float4 q0, q1;
  {
    const float* hp = h + (size_t)g * FF;
    q0 = *(const float4*)(hp + 4 * lane);
    q1 = *(const float4*)(hp + 256 + 4 * lane);
  }

  // contiguous quarter for this wave
  int len = e - s;
  int qlen = (len + 3) >> 2;
  int i0 = s + wid * qlen;
  int i1 = i0 + qlen; if (i1 > e) i1 = e;

  float m = -INFINITY, d = 0.f;
  float4 r0 = make_float4(0.f, 0.f, 0.f, 0.f);
  float4 r1 = make_float4(0.f, 0.f, 0.f, 0.f);

  int i = i0;
  for (; i + 4 <= i1; i += 4) {
    const float* xp = x + (size_t)i * FF + 4 * lane;
    float4 a00 = *(const float4*)(xp);
    float4 a01 = *(const float4*)(xp + 256);
    float4 a10 = *(const float4*)(xp + FF);
    float4 a11 = *(const float4*)(xp + FF + 256);
    float4 a20 = *(const float4*)(xp + 2*FF);
    float4 a21 = *(const float4*)(xp + 2*FF + 256);
    float4 a30 = *(const float4*)(xp + 3*FF);
    float4 a31 = *(const float4*)(xp + 3*FF + 256);
    float p0 = dotq_reduce(a00, a01, q0, q1);
    float p1 = dotq_reduce(a10, a11, q0, q1);
    float p2 = dotq_reduce(a20, a21, q0, q1);
    float p3 = dotq_reduce(a30, a31, q0, q1);
    float mnew = fmaxf(fmaxf(m, fmaxf(p0, p1)), fmaxf(p2, p3));
    float sc = __expf(m - mnew);          // m=-inf first time -> 0
    float w0 = __expf(p0 - mnew);
    float w1 = __expf(p1 - mnew);
    float w2 = __expf(p2 - mnew);
    float w3 = __expf(p3 - mnew);
    d = d * sc + ((w0 + w1) + (w2 + w3));
    r0.x = r0.x*sc + w0*a00.x + w1*a10.x + w2*a20.x + w3*a30.x;
    r0.y = r0.y*sc + w0*a00.y + w1*a10.y + w2*a20.y + w3*a30.y;
    r0.z = r0.z*sc + w0*a00.z + w1*a10.z + w2*a20.z + w3*a30.z;
    r0.w = r0.w*sc + w0*a00.w + w1*a10.w + w2*a20.w + w3*a30.w;
    r1.x = r1.x*sc + w0*a01.x + w1*a11.x + w2*a21.x + w3*a31.x;
    r1.y = r1.y*sc + w0*a01.y + w1*a11.y + w2*a21.y + w3*a31.y;
    r1.z = r1.z*sc + w0*a01.z + w1*a11.z + w2*a21.z + w3*a31.z;
    r1.w = r1.w*sc + w0*a01.w + w1*a11.w + w2*a21.w + w3*a31.w;
    m = mnew;
  }
  for (; i < i1; ++i) {                  // 0..3 remainder rows
    const float* xp = x + (size_t)i * FF + 4 * lane;
    float4 a0 = *(const float4*)(xp);
    float4 a1 = *(const float4*)(xp + 256);
    float p = dotq_reduce(a0, a1, q0, q1);
    float mnew = fmaxf(m, p);
    float sc = __expf(m - mnew);
    float w  = __expf(p - mnew);
    d = d * sc + w;
    r0.x = r0.x*sc + w*a0.x; r0.y = r0.y*sc + w*a0.y;
    r0.z = r0.z*sc + w*a0.z; r0.w = r0.w*sc + w*a0.w;
    r1.x = r1.x*sc + w*a1.x; r1.y = r1.y*sc + w*a1.y;
    r1.z = r1.z*sc + w*a1.z; r1.w = r1.w*sc + w*a1.w;
    m = mnew;
  }

  // ---- merge 4 wave partials ----
  if (lane == 0) { wm[wid] = m; wd[wid] = d; }
  *(float4*)&wrs[wid][4 * lane]       = r0;
  *(float4*)&wrs[wid][256 + 4 * lane] = r1;
  __syncthreads();

  float m0 = wm[0], m1 = wm[1], m2 = wm[2], m3 = wm[3];
  float ms = fmaxf(fmaxf(m0, m1), fmaxf(m2, m3));
  float s0 = (m0 == -INFINITY) ? 0.f : __expf(m0 - ms);
  float s1 = (m1 == -INFINITY) ? 0.f : __expf(m1 - ms);
  float s2 = (m2 == -INFINITY) ? 0.f : __expf(m2 - ms);
  float s3 = (m3 == -INFINITY) ? 0.f : __expf(m3 - ms);
  float dt = wd[0]*s0 + wd[1]*s1 + wd[2]*s2 + wd[3]*s3;
  float inv = (dt > 0.f) ? 1.f / dt : 0.f;

  int cc = tid * 2;                    // 256 threads x 2 cols = 512
  float2 v0 = *(float2*)&wrs[0][cc];
  float2 v1 = *(float2*)&wrs[1][cc];
  float2 v2 = *(float2*)&wrs[2][cc];
  float2 v3 = *(float2*)&wrs[3][cc];
  float rx = (v0.x*s0 + v1.x*s1 + v2.x*s2 + v3.x*s3) * inv;
  float ry = (v0.y*s0 + v1.y*s1 + v2.y*s2 + v3.y*s3) * inv;
  *(float2*)(qs_out + (size_t)g * G2F + FF + cc) = make_float2(rx, ry);

  // bf16-split r-part of next GEMM's A
  ushort2 hh, ll;
  hh.x = f2bf(rx); ll.x = f2bf(rx - bf2f(hh.x));
  hh.y = f2bf(ry); ll.y = f2bf(ry - bf2f(hh.y));
  *(ushort2*)(A_hi + (size_t)g * KC + FF + cc) = hh;
  *(ushort2*)(A_lo + (size_t)g * KC + FF + cc) = ll;
}

// ---------------------------------------------------------------------------
extern "C" void kernel_launch(void* const* d_in, const int* in_sizes, int n_in,
                              void* d_out, int out_size, void* d_ws, size_t ws_size,
                              hipStream_t stream) {
  const float* x    = (const float*)d_in[0];
  const int*   idx  = (const int*)d_in[1];
  const float* Wk   = (const float*)d_in[2];
  const float* Wr   = (const float*)d_in[3];
  const float* bias = (const float*)d_in[4];
  int N = in_sizes[1];
  int F = in_sizes[4] / 4;          // 512 (kernels hard-assume this)
  int G = out_size / (2 * F);       // 1000
  (void)n_in; (void)ws_size; (void)F;

  float* qstar = (float*)d_out;     // q_star lives in d_out (fully rewritten each iter)

  // workspace carve (all chunks 16B-multiple):
  char* p = (char*)d_ws;
  float*  h     = (float*)p;            p += (size_t)G * FF * 4;
  float*  c     = (float*)p;            p += (size_t)G * FF * 4;
  float*  z     = (float*)p;            p += (size_t)MPAD * G4F * 4;
  ushort* A_hi  = (ushort*)p;           p += (size_t)MPAD * KC * 2;
  ushort* A_lo  = (ushort*)p;           p += (size_t)MPAD * KC * 2;
  ushort* Wt_hi = (ushort*)p;           p += (size_t)G4F * KC * 2;
  ushort* Wt_lo = (ushort*)p;           p += (size_t)G4F * KC * 2;
  int*    segs  = (int*)p;              p += (size_t)G * 4;
  int*    sege  = (int*)p;

  hipMemsetAsync(segs, 0, 2 * sizeof(int) * (size_t)G, stream);
  seg_bounds_kernel<<<(N + 255) / 256, 256, 0, stream>>>(idx, N, segs, sege);

  // one-time combined-weight transpose+split (constant across iterations)
  prep_w_kernel<<<dim3(KC / 32, G4F / 32), 256, 0, stream>>>(Wk, Wr, Wt_hi, Wt_lo);

  dim3 ggrid((G + GBM - 1) / GBM, G4F / GBN);   // 16 x 32 = 512 blocks

  for (int it = 0; it < NITER; ++it) {
    if (it == 0) {
      // q_star = h = c = 0  =>  z = bias; GEMM provably skippable.
      gates_kernel<<<(G * FF + 255) / 256, 256, 0, stream>>>(z, bias, h, c, qstar, A_hi, A_lo, G, 1);
    } else {
      gemm_mfma_kernel<<<ggrid, 256, 0, stream>>>(A_hi, A_lo, Wt_hi, Wt_lo, z);
      gates_kernel<<<(G * FF + 255) / 256, 256, 0, stream>>>(z, bias, h, c, qstar, A_hi, A_lo, G, 0);
    }
    attn_fused_kernel<<<G, 256, 0, stream>>>(x, h, segs, sege, qstar, A_hi, A_lo);
  }
}